// Round 6
// baseline (521.160 us; speedup 1.0000x reference)
//
#include <hip/hip_runtime.h>

// FDTD rollout, temporally blocked (TS=16 steps/launch), occupancy-driven.
// Tile = 8x32 output, region = 40x64 halo. 1024 blocks x 320 threads
// (5 waves; wave = 8-row band, lane = column) -> 4 blocks/CU, 20 waves/CU,
// so independent blocks hide each other's barrier/LDS/store latency.
// Horizontal neighbors via DPP lane shifts; vertical via registers, with
// inter-wave boundary rows exchanged through LDS (double-buffered).

#define HH 512
#define WW 512
#define TR 8      // tile rows
#define TC 32     // tile cols
#define TS 16
#define NW 5      // waves per block (region rows = 40)
#define RPT 8     // rows per thread
#define PHC ((float)(2.0 * 3.1415926 * 100.0))

#if __has_builtin(__builtin_amdgcn_update_dpp)
__device__ __forceinline__ float nbrL(float x) {   // value from lane-1 (left)
    int i = __builtin_bit_cast(int, x);
    i = __builtin_amdgcn_update_dpp(i, i, 0x138, 0xf, 0xf, false); // wave_shr:1
    return __builtin_bit_cast(float, i);
}
__device__ __forceinline__ float nbrR(float x) {   // value from lane+1 (right)
    int i = __builtin_bit_cast(int, x);
    i = __builtin_amdgcn_update_dpp(i, i, 0x130, 0xf, 0xf, false); // wave_shl:1
    return __builtin_bit_cast(float, i);
}
#else
__device__ __forceinline__ float nbrL(float x) { return __shfl_up(x, 1, 64); }
__device__ __forceinline__ float nbrR(float x) { return __shfl_down(x, 1, 64); }
#endif

__global__ __launch_bounds__(320, 5)
void fdtd_occ(const float* __restrict__ prevF,
              const float* __restrict__ curF,
              const float* __restrict__ cmap,
              const int* __restrict__ locx,
              const int* __restrict__ locy,
              const int* __restrict__ pb,
              const int* __restrict__ pid2,
              float* __restrict__ out,
              int t0, int nk)
{
    __shared__ float sb[2][NW][2][64];   // [buf][wave][top/bottom row][col]

    const int lane = threadIdx.x & 63;
    const int w    = threadIdx.x >> 6;
    const int bx   = blockIdx.x & 15;     // col tile 0..15
    const int by   = blockIdx.x >> 4;     // row tile 0..63
    const int gx0  = bx * TC - TS;
    const int gy0  = by * TR - TS;
    const int gc   = gx0 + lane;
    const int R    = w * RPT;             // local row base

    const int lx0 = locx[0], ly0 = locy[0];
    const int lx1 = locx[1], ly1 = locy[1];
    const int lx2 = locx[2], ly2 = locy[2];
    const int Bn  = pb[0] * pid2[0];

    float cur[RPT], pv[RPT], rr[RPT], cv[RPT];
    bool  issrc[RPT];
    unsigned m0 = 0, m511 = 0;
    const bool colOK = (gc >= 0) & (gc < WW);

    #pragma unroll
    for (int j = 0; j < RPT; ++j) {
        const int gr = gy0 + R + j;
        float c = 0.f, ce = 0.f, pp = 0.f;
        if (colOK && gr >= 0 && gr < HH) {
            const int gi = gr * WW + gc;
            c  = cmap[gi];
            ce = curF[gi];
            pp = prevF[gi];
        }
        cur[j] = ce; pv[j] = pp; cv[j] = c;
        rr[j]  = 1.0e-8f * c * c;
        issrc[j] = (gr == lx0 && gc == ly0) || (gr == lx1 && gc == ly1) ||
                   (gr == lx2 && gc == ly2);
        if (gr == 0)      m0   |= (1u << j);
        if (gr == HH - 1) m511 |= (1u << j);
    }
    sb[0][w][0][lane] = cur[0];
    sb[0][w][1][lane] = cur[RPT - 1];
    __syncthreads();

    // clamped LDS slots for region-edge waves (garbage-safe halo)
    const int wup = (w == 0)      ? 0      : w - 1;
    const int sup = (w == 0)      ? 0      : 1;
    const int wdn = (w == NW - 1) ? NW - 1 : w + 1;
    const int sdn = (w == NW - 1) ? 1      : 0;

    const bool edge    = (bx == 0) | (bx == 15) | (by <= 2) | (by >= 61);
    const bool doStore = (w == 2) & (lane >= 16) & (lane < 48);
    const size_t rowOff = (size_t)(gy0 + 2 * RPT) * WW + gc;

    if (!edge) {
        // ----------------- interior blocks: branch-free stencil ------------
        for (int k = 1; k <= nk; ++k) {
            const int p = (k - 1) & 1;
            // wave-uniform validity: rows [R, R+8) vs trapezoid [k, 40-k)
            const bool active = (R + RPT > k) & (R < NW * RPT - k);
            if (active) {
                const float srcv =
                    1500.0f * __sinf(PHC * (float)(Bn + t0 + k + 1) * 1.0e-4f);
                const float upb = sb[p][wup][sup][lane];
                const float dnb = sb[p][wdn][sdn][lane];
                float nc[RPT];
                #pragma unroll
                for (int j = 0; j < RPT; ++j) {
                    const float c = cur[j];
                    const float u = (j == 0)       ? upb : cur[j - 1];
                    const float d = (j == RPT - 1) ? dnb : cur[j + 1];
                    const float l = nbrL(c);
                    const float r = nbrR(c);
                    float v = 2.f * c - pv[j] +
                              rr[j] * (((u + d) + (l + r)) - 4.f * c);
                    nc[j] = issrc[j] ? srcv : v;
                }
                sb[p ^ 1][w][0][lane] = nc[0];
                sb[p ^ 1][w][1][lane] = nc[RPT - 1];
                if (doStore) {
                    float* op = out + (size_t)(t0 + k - 1) * (size_t)(HH * WW)
                                    + rowOff;
                    #pragma unroll
                    for (int j = 0; j < RPT; ++j) op[j * WW] = nc[j];
                }
                #pragma unroll
                for (int j = 0; j < RPT; ++j) { pv[j] = cur[j]; cur[j] = nc[j]; }
            }
            __syncthreads();
        }
    } else {
        // ----------------- edge blocks: predicated boundary overrides ------
        const bool isC0   = (gc == 0);
        const bool isC511 = (gc == WW - 1);
        for (int k = 1; k <= nk; ++k) {
            const int p = (k - 1) & 1;
            const float srcv =
                1500.0f * __sinf(PHC * (float)(Bn + t0 + k + 1) * 1.0e-4f);
            const float upb = sb[p][wup][sup][lane];
            const float dnb = sb[p][wdn][sdn][lane];
            float nc[RPT];
            #pragma unroll
            for (int j = 0; j < RPT; ++j) {
                const float c = cur[j];
                const float u = (j == 0)       ? upb : cur[j - 1];
                const float d = (j == RPT - 1) ? dnb : cur[j + 1];
                const float l = nbrL(c);
                const float r = nbrR(c);
                float v = 2.f * c - pv[j] +
                          rr[j] * (((u + d) + (l + r)) - 4.f * c);
                v = issrc[j] ? srcv : v;
                // precedence (last wins): row0 < col0 < col511 < row511
                if ((m0 >> j) & 1u)   v = c - 1.0e-4f * cv[j] * (c - d);
                if (isC0)             v = c - 1.0e-4f * cv[j] * (c - r);
                if (isC511)           v = c - 1.0e-4f * cv[j] * (c - l);
                if ((m511 >> j) & 1u) v = c - 1.0e-4f * cv[j] * (c - u);
                nc[j] = v;
            }
            sb[p ^ 1][w][0][lane] = nc[0];
            sb[p ^ 1][w][1][lane] = nc[RPT - 1];
            if (doStore) {
                float* op = out + (size_t)(t0 + k - 1) * (size_t)(HH * WW)
                                + rowOff;
                #pragma unroll
                for (int j = 0; j < RPT; ++j) op[j * WW] = nc[j];
            }
            #pragma unroll
            for (int j = 0; j < RPT; ++j) { pv[j] = cur[j]; cur[j] = nc[j]; }
            __syncthreads();
        }
    }
}

extern "C" void kernel_launch(void* const* d_in, const int* in_sizes, int n_in,
                              void* d_out, int out_size, void* d_ws, size_t ws_size,
                              hipStream_t stream) {
    const float* in_out = (const float*)d_in[0];   // [steps+2, 1, 512, 512]
    const float* cmap   = (const float*)d_in[1];   // [1,1,512,512]
    const int*   locx   = (const int*)d_in[2];
    const int*   locy   = (const int*)d_in[3];
    const int*   pb     = (const int*)d_in[4];     // bsize1
    const int*   pid2   = (const int*)d_in[5];     // id2
    float* out = (float*)d_out;

    const int HW = HH * WW;
    const int steps = out_size / HW;
    const int nblocks = (WW / TC) * (HH / TR);     // 16 * 64 = 1024

    for (int t0 = 0; t0 < steps; t0 += TS) {
        const int nk = (steps - t0 < TS) ? (steps - t0) : TS;
        const float *prevF, *curF;
        if (t0 == 0) {
            prevF = in_out;
            curF  = in_out + HW;
        } else {
            prevF = out + (size_t)(t0 - 2) * HW;
            curF  = out + (size_t)(t0 - 1) * HW;
        }
        hipLaunchKernelGGL(fdtd_occ, dim3(nblocks), dim3(320), 0, stream,
                           prevF, curF, cmap, locx, locy, pb, pid2, out, t0, nk);
    }
}

// Round 7
// 248.362 us; speedup vs baseline: 2.0984x; 2.0984x over previous
//
#include <hip/hip_runtime.h>

// FDTD rollout, temporally blocked (TS=16 steps/launch).
// 256 blocks x 512 threads; block = 32x32 output tile via 64x64 halo region.
// Thread = 8-row x 1-col register strip (lane = column, wave = 8-row band).
// LDS holds only inter-wave boundary rows (double-buffered).
// Horizontal neighbors via DPP wave_shr:1 / wave_shl:1 (register path).
// KEY CHANGE vs r4: the per-step __syncthreads() (which drains vmcnt(0),
// putting HBM store latency on every step's critical path) is replaced by
// s_waitcnt lgkmcnt(0) + s_barrier -- LDS-only ordering; global stores
// stay in flight across steps.

#define HH 512
#define WW 512
#define TILE 32
#define TS 16
#define NW 8      // waves per block
#define RPT 8     // rows per thread
#define PHC ((float)(2.0 * 3.1415926 * 100.0))

// LDS-only barrier: all waves' ds_writes complete, nobody drains vmcnt.
#define LDS_BARRIER() asm volatile("s_waitcnt lgkmcnt(0)\n\ts_barrier" ::: "memory")

#if __has_builtin(__builtin_amdgcn_update_dpp)
__device__ __forceinline__ float nbrL(float x) {   // value from lane-1 (left)
    int i = __builtin_bit_cast(int, x);
    i = __builtin_amdgcn_update_dpp(i, i, 0x138, 0xf, 0xf, false); // wave_shr:1
    return __builtin_bit_cast(float, i);
}
__device__ __forceinline__ float nbrR(float x) {   // value from lane+1 (right)
    int i = __builtin_bit_cast(int, x);
    i = __builtin_amdgcn_update_dpp(i, i, 0x130, 0xf, 0xf, false); // wave_shl:1
    return __builtin_bit_cast(float, i);
}
#else
__device__ __forceinline__ float nbrL(float x) { return __shfl_up(x, 1, 64); }
__device__ __forceinline__ float nbrR(float x) { return __shfl_down(x, 1, 64); }
#endif

__global__ __launch_bounds__(512)
void fdtd_nosync(const float* __restrict__ prevF,
                 const float* __restrict__ curF,
                 const float* __restrict__ cmap,
                 const int* __restrict__ locx,
                 const int* __restrict__ locy,
                 const int* __restrict__ pb,
                 const int* __restrict__ pid2,
                 float* __restrict__ out,
                 int t0, int nk)
{
    __shared__ float sb[2][NW][2][64];   // [buf][wave][top/bottom row][col]

    const int lane = threadIdx.x & 63;
    const int w    = threadIdx.x >> 6;
    const int bx   = blockIdx.x & 15;
    const int by   = blockIdx.x >> 4;
    const int gx0  = bx * TILE - TS;
    const int gy0  = by * TILE - TS;
    const int gc   = gx0 + lane;
    const int R    = w * RPT;            // local row base

    const int lx0 = locx[0], ly0 = locy[0];
    const int lx1 = locx[1], ly1 = locy[1];
    const int lx2 = locx[2], ly2 = locy[2];
    const int Bn  = pb[0] * pid2[0];

    float cur[RPT], pv[RPT], rr[RPT], cv[RPT];
    bool  issrc[RPT];
    unsigned m0 = 0, m511 = 0;
    const bool colOK = (gc >= 0) & (gc < WW);

    #pragma unroll
    for (int j = 0; j < RPT; ++j) {
        const int gr = gy0 + R + j;
        float c = 0.f, ce = 0.f, pp = 0.f;
        if (colOK && gr >= 0 && gr < HH) {
            const int gi = gr * WW + gc;
            c  = cmap[gi];
            ce = curF[gi];
            pp = prevF[gi];
        }
        cur[j] = ce; pv[j] = pp; cv[j] = c;
        rr[j]  = 1.0e-8f * c * c;
        issrc[j] = (gr == lx0 && gc == ly0) || (gr == lx1 && gc == ly1) ||
                   (gr == lx2 && gc == ly2);
        if (gr == 0)      m0   |= (1u << j);
        if (gr == HH - 1) m511 |= (1u << j);
    }
    sb[0][w][0][lane] = cur[0];
    sb[0][w][1][lane] = cur[RPT - 1];
    __syncthreads();

    // clamped LDS slots for region-edge waves (garbage-safe halo)
    const int wup = (w == 0)      ? 0      : w - 1;
    const int sup = (w == 0)      ? 0      : 1;
    const int wdn = (w == NW - 1) ? NW - 1 : w + 1;
    const int sdn = (w == NW - 1) ? 1      : 0;

    const bool edge    = (bx == 0) | (bx == 15) | (by == 0) | (by == 15);
    const bool doStore = (w >= 2) & (w <= 5) & (lane >= 16) & (lane < 48);
    const size_t rowOff = (size_t)(gy0 + R) * WW + gc;

    if (!edge) {
        // ----------------- interior blocks: branch-free stencil ------------
        #pragma unroll 2
        for (int k = 1; k <= nk; ++k) {
            const int p = (k - 1) & 1;
            const float srcv =
                1500.0f * __sinf(PHC * (float)(Bn + t0 + k + 1) * 1.0e-4f);
            const float upb = sb[p][wup][sup][lane];
            const float dnb = sb[p][wdn][sdn][lane];
            float nc[RPT];
            #pragma unroll
            for (int j = 0; j < RPT; ++j) {
                const float c = cur[j];
                const float u = (j == 0)       ? upb : cur[j - 1];
                const float d = (j == RPT - 1) ? dnb : cur[j + 1];
                const float l = nbrL(c);
                const float r = nbrR(c);
                float v = 2.f * c - pv[j] + rr[j] * (((u + d) + (l + r)) - 4.f * c);
                nc[j] = issrc[j] ? srcv : v;
            }
            sb[p ^ 1][w][0][lane] = nc[0];
            sb[p ^ 1][w][1][lane] = nc[RPT - 1];
            if (doStore) {
                float* op = out + (size_t)(t0 + k - 1) * (size_t)(HH * WW) + rowOff;
                #pragma unroll
                for (int j = 0; j < RPT; ++j) op[j * WW] = nc[j];
            }
            #pragma unroll
            for (int j = 0; j < RPT; ++j) { pv[j] = cur[j]; cur[j] = nc[j]; }
            LDS_BARRIER();
        }
    } else {
        // ----------------- edge blocks: predicated boundary overrides ------
        const bool isC0   = (gc == 0);
        const bool isC511 = (gc == WW - 1);
        #pragma unroll 2
        for (int k = 1; k <= nk; ++k) {
            const int p = (k - 1) & 1;
            const float srcv =
                1500.0f * __sinf(PHC * (float)(Bn + t0 + k + 1) * 1.0e-4f);
            const float upb = sb[p][wup][sup][lane];
            const float dnb = sb[p][wdn][sdn][lane];
            float nc[RPT];
            #pragma unroll
            for (int j = 0; j < RPT; ++j) {
                const float c = cur[j];
                const float u = (j == 0)       ? upb : cur[j - 1];
                const float d = (j == RPT - 1) ? dnb : cur[j + 1];
                const float l = nbrL(c);
                const float r = nbrR(c);
                float v = 2.f * c - pv[j] + rr[j] * (((u + d) + (l + r)) - 4.f * c);
                v = issrc[j] ? srcv : v;
                // precedence (last wins): row0 < col0 < col511 < row511
                if ((m0 >> j) & 1u)   v = c - 1.0e-4f * cv[j] * (c - d);
                if (isC0)             v = c - 1.0e-4f * cv[j] * (c - r);
                if (isC511)           v = c - 1.0e-4f * cv[j] * (c - l);
                if ((m511 >> j) & 1u) v = c - 1.0e-4f * cv[j] * (c - u);
                nc[j] = v;
            }
            sb[p ^ 1][w][0][lane] = nc[0];
            sb[p ^ 1][w][1][lane] = nc[RPT - 1];
            if (doStore) {
                float* op = out + (size_t)(t0 + k - 1) * (size_t)(HH * WW) + rowOff;
                #pragma unroll
                for (int j = 0; j < RPT; ++j) op[j * WW] = nc[j];
            }
            #pragma unroll
            for (int j = 0; j < RPT; ++j) { pv[j] = cur[j]; cur[j] = nc[j]; }
            LDS_BARRIER();
        }
    }
}

extern "C" void kernel_launch(void* const* d_in, const int* in_sizes, int n_in,
                              void* d_out, int out_size, void* d_ws, size_t ws_size,
                              hipStream_t stream) {
    const float* in_out = (const float*)d_in[0];   // [steps+2, 1, 512, 512]
    const float* cmap   = (const float*)d_in[1];   // [1,1,512,512]
    const int*   locx   = (const int*)d_in[2];
    const int*   locy   = (const int*)d_in[3];
    const int*   pb     = (const int*)d_in[4];     // bsize1
    const int*   pid2   = (const int*)d_in[5];     // id2
    float* out = (float*)d_out;

    const int HW = HH * WW;
    const int steps = out_size / HW;
    const int nblocks = (HH / TILE) * (WW / TILE); // 256

    for (int t0 = 0; t0 < steps; t0 += TS) {
        const int nk = (steps - t0 < TS) ? (steps - t0) : TS;
        const float *prevF, *curF;
        if (t0 == 0) {
            prevF = in_out;
            curF  = in_out + HW;
        } else {
            prevF = out + (size_t)(t0 - 2) * HW;
            curF  = out + (size_t)(t0 - 1) * HW;
        }
        hipLaunchKernelGGL(fdtd_nosync, dim3(nblocks), dim3(512), 0, stream,
                           prevF, curF, cmap, locx, locy, pb, pid2, out, t0, nk);
    }
}